// Round 1
// baseline (128.562 us; speedup 1.0000x reference)
//
#include <hip/hip_runtime.h>

#define BLOCK 256
#define GRID  2048

__device__ __forceinline__ float frcp(float x) { return __builtin_amdgcn_rcpf(x); }

// exp_se3: twist (w,v) -> R (row-major 3x3), t
__device__ __forceinline__ void expse3(float wx, float wy, float wz,
                                       float vx, float vy, float vz,
                                       float* R, float* t)
{
    float t2 = wx*wx + wy*wy + wz*wz;
    bool  sm = t2 < 1e-8f;
    float t2s = sm ? 1.0f : t2;
    float th  = sqrtf(t2s);
    float s, c;
    __sincosf(th, &s, &c);
    float rth  = frcp(th);
    float rt2s = rth * rth;            // 1/t2s (th = sqrt(t2s))
    float A = sm ? 1.0f - t2*(1.0f/6.0f)                 : s * rth;
    float B = sm ? 0.5f - t2*(1.0f/24.0f)                : (1.0f - c) * rt2s;
    float C = sm ? (1.0f/6.0f) - t2*(1.0f/120.0f)        : (1.0f - s*rth) * rt2s; // (th-s)/(t2s*th)
    // K^2 = w w^T - t2 I
    float Bxy = B*wx*wy, Bxz = B*wx*wz, Byz = B*wy*wz;
    R[0] = 1.0f + B*(wx*wx - t2); R[1] = Bxy - A*wz;            R[2] = Bxz + A*wy;
    R[3] = Bxy + A*wz;            R[4] = 1.0f + B*(wy*wy - t2); R[5] = Byz - A*wx;
    R[6] = Bxz - A*wy;            R[7] = Byz + A*wx;            R[8] = 1.0f + B*(wz*wz - t2);
    float Cxy = C*wx*wy, Cxz = C*wx*wz, Cyz = C*wy*wz;
    float V0 = 1.0f + C*(wx*wx - t2), V1 = Cxy - B*wz,            V2 = Cxz + B*wy;
    float V3 = Cxy + B*wz,            V4 = 1.0f + C*(wy*wy - t2), V5 = Cyz - B*wx;
    float V6 = Cxz - B*wy,            V7 = Cyz + B*wx,            V8 = 1.0f + C*(wz*wz - t2);
    t[0] = V0*vx + V1*vy + V2*vz;
    t[1] = V3*vx + V4*vy + V5*vz;
    t[2] = V6*vx + V7*vy + V8*vz;
}

__global__ void __launch_bounds__(BLOCK)
se3_loss_kernel(const float* __restrict__ pred, const float* __restrict__ targ,
                float* __restrict__ out, int n, float invN)
{
    float acc = 0.0f;
    int stride = gridDim.x * blockDim.x;
    for (int i = blockIdx.x * blockDim.x + threadIdx.x; i < n; i += stride) {
        const float2* p2 = reinterpret_cast<const float2*>(pred) + 3 * (size_t)i;
        const float2* q2 = reinterpret_cast<const float2*>(targ) + 3 * (size_t)i;
        float2 pa = p2[0], pb = p2[1], pc = p2[2];
        float2 qa = q2[0], qb = q2[1], qc = q2[2];

        float Rp[9], tp[3], Rt[9], tt[3];
        expse3(pa.x, pa.y, pb.x, pb.y, pc.x, pc.y, Rp, tp);
        expse3(qa.x, qa.y, qb.x, qb.y, qc.x, qc.y, Rt, tt);

        // Rd = Rp^T * Rt ; td = Rp^T * (tt - tp)
        float d0 = tt[0] - tp[0], d1 = tt[1] - tp[1], d2 = tt[2] - tp[2];
        float Rd[9];
        #pragma unroll
        for (int ii = 0; ii < 3; ii++)
            #pragma unroll
            for (int kk = 0; kk < 3; kk++)
                Rd[ii*3+kk] = Rp[0+ii]*Rt[0+kk] + Rp[3+ii]*Rt[3+kk] + Rp[6+ii]*Rt[6+kk];
        float td0 = Rp[0]*d0 + Rp[3]*d1 + Rp[6]*d2;
        float td1 = Rp[1]*d0 + Rp[4]*d1 + Rp[7]*d2;
        float td2 = Rp[2]*d0 + Rp[5]*d1 + Rp[8]*d2;

        // log_se3
        float tr = Rd[0] + Rd[4] + Rd[8];
        float c  = fminf(fmaxf((tr - 1.0f) * 0.5f, -1.0f + 1e-7f), 1.0f - 1e-7f);
        float th = acosf(c);
        bool  sm = th < 1e-4f;
        float s  = __sinf(th);
        float ths = sm ? 1.0f : th;
        float ss  = sm ? 1.0f : s;
        float coef = sm ? 0.5f + th*th*(1.0f/12.0f) : th * 0.5f * frcp(ss);
        float wx = coef * (Rd[7] - Rd[5]);
        float wy = coef * (Rd[2] - Rd[6]);
        float wz = coef * (Rd[3] - Rd[1]);
        float w2 = wx*wx + wy*wy + wz*wz;
        float omc = sm ? 1.0f : 1.0f - c;
        float rths = frcp(ths);
        float D = sm ? (1.0f/12.0f)
                     : (1.0f - th*s*0.5f*frcp(omc)) * rths * rths;
        // Vinv = I - 0.5 K + D K^2,  K^2 = w w^T - w2 I
        float Dxy = D*wx*wy, Dxz = D*wx*wz, Dyz = D*wy*wz;
        float Vi0 = 1.0f + D*(wx*wx - w2), Vi1 =  0.5f*wz + Dxy,           Vi2 = -0.5f*wy + Dxz;
        float Vi3 = -0.5f*wz + Dxy,        Vi4 = 1.0f + D*(wy*wy - w2),    Vi5 =  0.5f*wx + Dyz;
        float Vi6 =  0.5f*wy + Dxz,        Vi7 = -0.5f*wx + Dyz,           Vi8 = 1.0f + D*(wz*wz - w2);
        float vx = Vi0*td0 + Vi1*td1 + Vi2*td2;
        float vy = Vi3*td0 + Vi4*td1 + Vi5*td2;
        float vz = Vi6*td0 + Vi7*td1 + Vi8*td2;

        acc += w2 + vx*vx + vy*vy + vz*vz;
    }

    // wave-64 reduction
    #pragma unroll
    for (int off = 32; off; off >>= 1) acc += __shfl_down(acc, off, 64);
    __shared__ float wsum[BLOCK / 64];
    int lane = threadIdx.x & 63, wid = threadIdx.x >> 6;
    if (lane == 0) wsum[wid] = acc;
    __syncthreads();
    if (threadIdx.x == 0) {
        float s = 0.0f;
        #pragma unroll
        for (int k = 0; k < BLOCK / 64; k++) s += wsum[k];
        atomicAdd(out, s * invN);
    }
}

extern "C" void kernel_launch(void* const* d_in, const int* in_sizes, int n_in,
                              void* d_out, int out_size, void* d_ws, size_t ws_size,
                              hipStream_t stream) {
    const float* pred = (const float*)d_in[0];
    const float* targ = (const float*)d_in[1];
    float* out = (float*)d_out;
    int n = in_sizes[0] / 6;
    hipMemsetAsync(out, 0, (size_t)out_size * sizeof(float), stream);
    se3_loss_kernel<<<GRID, BLOCK, 0, stream>>>(pred, targ, out, n, 1.0f / (float)n);
}